// Round 8
// baseline (672.010 us; speedup 1.0000x reference)
//
#include <hip/hip_runtime.h>

static constexpr int KC   = 9;    // kernel bins
static constexpr int CIN  = 32;   // input channels
static constexpr int CA   = 24;   // branch-a out channels
static constexpr int CB   = 8;    // branch-b out channels
static constexpr int COUT = 32;   // CA + CB
static constexpr int WSTR = KC * CIN + 4;   // 292 dwords: packed-W row stride
static constexpr int SPP  = 2 * KC * CIN;   // 576 dwords of S per point (Sa|Sb)

// ---------------------------------------------------------------------------
// Kernel 1: CSR row pointer from sorted neighbors_out_index.
// ---------------------------------------------------------------------------
__global__ void build_rowptr(const int* __restrict__ oidx, int* __restrict__ rp,
                             int E, int nout) {
    int e = blockIdx.x * blockDim.x + threadIdx.x;
    if (e >= E) return;
    int cur  = oidx[e];
    int prev = (e == 0) ? -1 : oidx[e - 1];
    for (int id = prev + 1; id <= cur; ++id) rp[id] = e;
    if (e == E - 1) {
        for (int id = cur + 1; id <= nout; ++id) rp[id] = E;
    }
}

// ---------------------------------------------------------------------------
// Kernel 2: pack W_a [9][32][24], W_b [9][32][8] into Wt[f][k][c], row
// stride WSTR dwords (f-major), for the per-feature epilogue.
// ---------------------------------------------------------------------------
__global__ void pack_weights(const float* __restrict__ Wa,
                             const float* __restrict__ Wb,
                             float* __restrict__ Wt) {
    int t = blockIdx.x * blockDim.x + threadIdx.x;
    if (t >= COUT * KC * CIN) return;
    int f = t / (KC * CIN);
    int r = t % (KC * CIN);            // k*32 + c
    float v = (f < CA) ? Wa[r * CA + f] : Wb[r * CB + (f - CA)];
    Wt[f * WSTR + r] = v;
}

// ---------------------------------------------------------------------------
// Kernel A: S-tile accumulation at FULL occupancy.
// 256 threads = 8 half-waves; half-wave hw owns point p0+hw exclusively
// (rp partition, noidx never read). LDS = 18.4 KB only -> 8 blocks/CU =
// 32 waves/CU. ds_add bank == c: conflict-free. S tiles + impAcc streamed
// out with plain coalesced stores (no global atomics, no memset needed).
// ---------------------------------------------------------------------------
__global__ __launch_bounds__(256) void accum_S(
    const float* __restrict__ feats, const float* __restrict__ importance,
    const int* __restrict__ nidx, const int* __restrict__ nkidx,
    const int* __restrict__ rp,
    float* __restrict__ S, float* __restrict__ impAcc, int nout)
{
    __shared__ float sS[8][SPP];       // 18432 B
    const int tid = threadIdx.x;
    const int hw  = tid >> 5;          // half-wave id 0..7 == point slot
    const int c   = tid & 31;          // channel lane
    const int p0  = blockIdx.x * 8;
    const int n   = p0 + hw;

    // zero tiles
    {
        float* pS = &sS[0][0];
        for (int i = tid; i < 8 * SPP; i += 256) pS[i] = 0.f;
    }
    __syncthreads();

    if (n < nout) {
        const int start = rp[n];
        const int end   = rp[n + 1];
        float* base = &sS[hw][0];
        float accImp = 0.f;

        int e = start;
        for (; e + 4 <= end; e += 4) {
            // metadata: uniform per half-wave, contiguous stream
            int i0 = nidx[e],     i1 = nidx[e + 1];
            int i2 = nidx[e + 2], i3 = nidx[e + 3];
            int q0 = nkidx[e],     q1 = nkidx[e + 1];
            int q2 = nkidx[e + 2], q3 = nkidx[e + 3];
            float m0 = importance[i0], m1 = importance[i1];
            float m2 = importance[i2], m3 = importance[i3];
            // 4 independent coalesced 128B row gathers in flight
            float f0 = feats[(size_t)i0 * CIN + c];
            float f1 = feats[(size_t)i1 * CIN + c];
            float f2 = feats[(size_t)i2 * CIN + c];
            float f3 = feats[(size_t)i3 * CIN + c];
            accImp += (m0 + m1) + (m2 + m3);
            atomicAdd(base + q0 * CIN + c, f0);
            atomicAdd(base + KC * CIN + q0 * CIN + c, f0 * m0);
            atomicAdd(base + q1 * CIN + c, f1);
            atomicAdd(base + KC * CIN + q1 * CIN + c, f1 * m1);
            atomicAdd(base + q2 * CIN + c, f2);
            atomicAdd(base + KC * CIN + q2 * CIN + c, f2 * m2);
            atomicAdd(base + q3 * CIN + c, f3);
            atomicAdd(base + KC * CIN + q3 * CIN + c, f3 * m3);
        }
        for (; e < end; ++e) {
            int   i0 = nidx[e], q0 = nkidx[e];
            float m0 = importance[i0];
            float f0 = feats[(size_t)i0 * CIN + c];
            accImp += m0;
            atomicAdd(base + q0 * CIN + c, f0);
            atomicAdd(base + KC * CIN + q0 * CIN + c, f0 * m0);
        }
        // every lane of the half saw every edge: accImp is the full sum
        if (c == 0) impAcc[n] = accImp;
    }
    __syncthreads();

    // stream tiles to global (coalesced float4; only valid points)
    int npts = nout - p0; if (npts > 8) npts = 8;
    if (npts > 0) {
        const float4* src = reinterpret_cast<const float4*>(&sS[0][0]);
        float4*       dst = reinterpret_cast<float4*>(S + (size_t)p0 * SPP);
        const int nf4 = npts * (SPP / 4);
        for (int i = tid; i < nf4; i += 256) dst[i] = src[i];
    }
}

// ---------------------------------------------------------------------------
// Kernel B: per-feature epilogue. 512 threads / 8 waves (one point each),
// W in LDS (37.4 KB -> 4 blocks/CU = 32 waves). S layout [n][2][288].
// ---------------------------------------------------------------------------
__global__ __launch_bounds__(512) void epilogue(
    const float* __restrict__ S, const float* __restrict__ impAcc,
    const float* __restrict__ Wt, const float* __restrict__ ba,
    const float* __restrict__ bb,
    float* __restrict__ outf, float* __restrict__ outimp, int nout)
{
    __shared__ __align__(16) float sW[COUT * WSTR];   // 37376 B
    {
        const float4* src = reinterpret_cast<const float4*>(Wt);
        float4*       dst = reinterpret_cast<float4*>(sW);
        for (int i = threadIdx.x; i < COUT * WSTR / 4; i += 512) dst[i] = src[i];
    }
    __syncthreads();

    const int wave = threadIdx.x >> 6;
    const int lane = threadIdx.x & 63;
    const int f    = lane & 31;
    const int h    = lane >> 5;
    const int n    = blockIdx.x * 8 + wave;
    if (n >= nout) return;

    float impTot = impAcc[n];
    float denom  = impTot > 0.f ? impTot : 1.f;

    const float* Sbase = S + (size_t)n * SPP + ((f < CA) ? 0 : KC * CIN);
    const float* Wbase = sW + f * WSTR;
    float acc0 = 0.f, acc1 = 0.f, acc2 = 0.f, acc3 = 0.f;
#pragma unroll
    for (int k = 0; k < KC; ++k) {
        int off = k * CIN + h * 16;
        float4 s0 = *reinterpret_cast<const float4*>(Sbase + off);
        float4 s1 = *reinterpret_cast<const float4*>(Sbase + off + 4);
        float4 s2 = *reinterpret_cast<const float4*>(Sbase + off + 8);
        float4 s3 = *reinterpret_cast<const float4*>(Sbase + off + 12);
        float4 w0 = *reinterpret_cast<const float4*>(Wbase + off);
        float4 w1 = *reinterpret_cast<const float4*>(Wbase + off + 4);
        float4 w2 = *reinterpret_cast<const float4*>(Wbase + off + 8);
        float4 w3 = *reinterpret_cast<const float4*>(Wbase + off + 12);
        acc0 = fmaf(s0.x, w0.x, fmaf(s0.y, w0.y, fmaf(s0.z, w0.z, fmaf(s0.w, w0.w, acc0))));
        acc1 = fmaf(s1.x, w1.x, fmaf(s1.y, w1.y, fmaf(s1.z, w1.z, fmaf(s1.w, w1.w, acc1))));
        acc2 = fmaf(s2.x, w2.x, fmaf(s2.y, w2.y, fmaf(s2.z, w2.z, fmaf(s2.w, w2.w, acc2))));
        acc3 = fmaf(s3.x, w3.x, fmaf(s3.y, w3.y, fmaf(s3.z, w3.z, fmaf(s3.w, w3.w, acc3))));
    }
    float acc = (acc0 + acc1) + (acc2 + acc3);
    float tot = acc + __shfl_xor(acc, 32, 64);   // combine channel halves

    if (h == 0) {
        float res = (f < CA) ? (tot + ba[f]) : (tot / denom + bb[f - CA]);
        outf[(size_t)n * COUT + f] = fmaxf(res, 0.f);
    }
    if (lane == 0) outimp[n] = impTot;
}

// ===========================================================================
// Fallback (round-6 fused kernel) if ws can't hold the S scratch.
// ===========================================================================
static constexpr int PPB = 16;
static constexpr int TPB = 512;
static constexpr int NHW = TPB / 32;

__global__ __launch_bounds__(TPB) void fused_block(
    const float* __restrict__ feats, const float* __restrict__ importance,
    const float* __restrict__ Wt, const float* __restrict__ ba,
    const float* __restrict__ bb,
    const int* __restrict__ nidx, const int* __restrict__ nkidx,
    const int* __restrict__ noidx, const int* __restrict__ rp,
    float* __restrict__ outf, float* __restrict__ outimp, int nout)
{
    __shared__ __align__(16) float sW[COUT * WSTR];
    __shared__ __align__(16) float sS[PPB][2][KC * CIN];
    __shared__ float sImp[PPB];

    const int tid = threadIdx.x;
    const int hw  = tid >> 5;
    const int c   = tid & 31;
    const int p0  = blockIdx.x * PPB;

    {
        const float4* src = reinterpret_cast<const float4*>(Wt);
        float4*       dst = reinterpret_cast<float4*>(sW);
        for (int i = tid; i < COUT * WSTR / 4; i += TPB) dst[i] = src[i];
        float* pS = &sS[0][0][0];
        for (int i = tid; i < PPB * 2 * KC * CIN; i += TPB) pS[i] = 0.f;
        if (tid < PPB) sImp[tid] = 0.f;
    }
    __syncthreads();

    const int pend   = (p0 + PPB < nout) ? (p0 + PPB) : nout;
    const int estart = rp[p0];
    const int eend   = rp[pend];
    const int cnt    = eend - estart;
    const int per    = (cnt + NHW - 1) / NHW;
    int a = estart + hw * per;
    int b = a + per; if (b > eend) b = eend;

    float* S0 = &sS[0][0][0];
    for (int e = a; e < b; ++e) {
        int   n0 = noidx[e], i0 = nidx[e], q0 = nkidx[e];
        float m0 = importance[i0];
        float f0 = feats[(size_t)i0 * CIN + c];
        float* bp = S0 + (n0 - p0) * (2 * KC * CIN) + q0 * CIN + c;
        atomicAdd(bp, f0);
        atomicAdd(bp + KC * CIN, f0 * m0);
        if (c == 0) atomicAdd(&sImp[n0 - p0], m0);
    }
    __syncthreads();

    const int wave = tid >> 6;
    const int lane = tid & 63;
    const int f    = lane & 31;
    const int h    = lane >> 5;
#pragma unroll
    for (int rep = 0; rep < 2; ++rep) {
        const int slot = wave * 2 + rep;
        const int n    = p0 + slot;
        if (n >= nout) break;
        float impTot = sImp[slot];
        float denom  = impTot > 0.f ? impTot : 1.f;
        const float* Sbase = &sS[slot][(f < CA) ? 0 : 1][0];
        const float* Wbase = sW + f * WSTR;
        float acc = 0.f;
#pragma unroll
        for (int k = 0; k < KC; ++k) {
            int off = k * CIN + h * 16;
#pragma unroll
            for (int j = 0; j < 16; ++j) acc = fmaf(Sbase[off + j], Wbase[off + j], acc);
        }
        float tot = acc + __shfl_xor(acc, 32, 64);
        if (h == 0) {
            float res = (f < CA) ? (tot + ba[f]) : (tot / denom + bb[f - CA]);
            outf[(size_t)n * COUT + f] = fmaxf(res, 0.f);
        }
        if (lane == 0) outimp[n] = impTot;
    }
}

// ---------------------------------------------------------------------------
extern "C" void kernel_launch(void* const* d_in, const int* in_sizes, int n_in,
                              void* d_out, int out_size, void* d_ws, size_t ws_size,
                              hipStream_t stream) {
    const float* feats      = (const float*)d_in[0];
    const float* importance = (const float*)d_in[1];
    const float* Wa         = (const float*)d_in[2];
    const float* ba         = (const float*)d_in[3];
    const float* Wb         = (const float*)d_in[4];
    const float* bb         = (const float*)d_in[5];
    const int*   nidx       = (const int*)d_in[6];
    const int*   nkidx      = (const int*)d_in[7];
    const int*   noidx      = (const int*)d_in[8];

    const int E    = in_sizes[6];
    const int nout = out_size / (COUT + 1);

    float* outf   = (float*)d_out;
    float* outimp = outf + (size_t)nout * COUT;

    // ws layout: S [nout*576 f] | impAcc [nout f] | Wt | rp [(nout+1) i]
    const size_t off_imp = ((size_t)nout * SPP * sizeof(float) + 255) & ~(size_t)255;
    const size_t off_wt  = (off_imp + (size_t)nout * sizeof(float) + 255) & ~(size_t)255;
    const size_t off_rp  = (off_wt + (size_t)COUT * WSTR * sizeof(float) + 255) & ~(size_t)255;
    const size_t need    = off_rp + (size_t)(nout + 1) * sizeof(int);

    if (ws_size >= need) {
        float* S      = (float*)d_ws;
        float* impAcc = (float*)((char*)d_ws + off_imp);
        float* Wt     = (float*)((char*)d_ws + off_wt);
        int*   rp     = (int*)((char*)d_ws + off_rp);

        build_rowptr<<<(E + 255) / 256, 256, 0, stream>>>(noidx, rp, E, nout);
        pack_weights<<<(COUT * KC * CIN + 255) / 256, 256, 0, stream>>>(Wa, Wb, Wt);
        accum_S<<<(nout + 7) / 8, 256, 0, stream>>>(
            feats, importance, nidx, nkidx, rp, S, impAcc, nout);
        epilogue<<<(nout + 7) / 8, 512, 0, stream>>>(
            S, impAcc, Wt, ba, bb, outf, outimp, nout);
    } else {
        int*   rp = (int*)d_ws;
        size_t rp_bytes = ((size_t)(nout + 1) * sizeof(int) + 255) & ~(size_t)255;
        float* Wt = (float*)((char*)d_ws + rp_bytes);

        build_rowptr<<<(E + 255) / 256, 256, 0, stream>>>(noidx, rp, E, nout);
        pack_weights<<<(COUT * KC * CIN + 255) / 256, 256, 0, stream>>>(Wa, Wb, Wt);
        fused_block<<<(nout + PPB - 1) / PPB, TPB, 0, stream>>>(
            feats, importance, Wt, ba, bb, nidx, nkidx, noidx, rp,
            outf, outimp, nout);
    }
}